// Round 4
// baseline (807.597 us; speedup 1.0000x reference)
//
#include <hip/hip_runtime.h>
#include <cstdint>
#include <cstddef>

// Problem constants
constexpr int HWSZ = 65536;                       // 256*256 pixels per image
constexpr size_t CH_ELEMS = (size_t)304 * HWSZ;   // per-batch 304-channel buffer elems
constexpr int WT_H_ELEMS = 64 * 304;
constexpr int WT_P_ELEMS = 228 * 64;

#define C1F 0.70710678118654752f
#define S2F 1.41421356237309505f

// float4 helpers
__device__ __forceinline__ float4 f4(float v) { return make_float4(v, v, v, v); }
__device__ __forceinline__ float4 operator+(float4 a, float4 b) { return make_float4(a.x+b.x, a.y+b.y, a.z+b.z, a.w+b.w); }
__device__ __forceinline__ float4 operator-(float4 a, float4 b) { return make_float4(a.x-b.x, a.y-b.y, a.z-b.z, a.w-b.w); }
__device__ __forceinline__ float4 operator*(float4 a, float4 b) { return make_float4(a.x*b.x, a.y*b.y, a.z*b.z, a.w*b.w); }
__device__ __forceinline__ float4& operator+=(float4& a, float4 b) { a.x+=b.x; a.y+=b.y; a.z+=b.z; a.w+=b.w; return a; }

// ---------------- prep: transpose weights for scalar-load GEMMs ----------------
__global__ __launch_bounds__(256) void k_prep(const float* __restrict__ wh,
                                              const float* __restrict__ wp,
                                              float* __restrict__ wt_h,
                                              float* __restrict__ wt_p) {
    int i = blockIdx.x * 256 + threadIdx.x;
    if (i < 64 * 304) {            // wh is [o=304][k=64] -> wt_h[k][o]
        int o = i / 64, k = i % 64;
        wt_h[k * 304 + o] = wh[i];
    }
    int j = i - 64 * 304;
    if (j >= 0 && j < 64 * 228) {  // wp is [o=64][c=228] -> wt_p[cc][o]
        int o = j / 228, cc = j % 228;
        wt_p[cc * 64 + o] = wp[j];
    }
}

// ---------------- 1x1 conv (one batch); chunk tt holds matched q/k/v/vv triplets ----------------
// chunk local layout: [g=0..3][19][HWSZ]; global out-channel = 76*g + tt19 + i
__global__ __launch_bounds__(256) void k_conv1c(const float* __restrict__ xb,   // [64][65536]
                                                const float* __restrict__ wt,   // [k=64][o=304]
                                                float* __restrict__ chunk,      // [76][65536]
                                                int tt19) {
    int sp = blockIdx.x * 256 + threadIdx.x;   // 0..65535
    float xv[64];
#pragma unroll
    for (int k = 0; k < 64; k++) xv[k] = xb[(size_t)k * HWSZ + sp];
    for (int h = 0; h < 2; h++) {
        int g = blockIdx.y * 2 + h;                // group 0..3 (q,k,v,vv)
        int gbase = 76 * g + tt19;                 // global out-channel base
        float acc[19];
#pragma unroll
        for (int i = 0; i < 19; i++) acc[i] = 0.f;
#pragma unroll
        for (int k = 0; k < 64; k++) {
            float xs = xv[k];
            const float* wrow = wt + k * 304 + gbase;   // uniform -> s_load
#pragma unroll
            for (int i = 0; i < 19; i++) acc[i] = fmaf(xs, wrow[i], acc[i]);
        }
#pragma unroll
        for (int i = 0; i < 19; i++) chunk[(size_t)(g * 19 + i) * HWSZ + sp] = acc[i];
    }
}

// ---------------- small FFT helpers (verified R2/R3) ----------------
__device__ __forceinline__ void rfft8(const float a[8], float Xr[5], float Xi[5]) {
    float u0 = a[0] + a[4], u1 = a[0] - a[4];
    float u2 = a[2] + a[6], u3 = a[2] - a[6];
    float u4 = a[1] + a[5], p  = a[1] - a[5];
    float u6 = a[3] + a[7], q  = a[3] - a[7];
    Xr[0] = u0 + u2 + u4 + u6;        Xi[0] = 0.f;
    Xr[1] = u1 + C1F * (p - q);       Xi[1] = -u3 - C1F * (p + q);
    Xr[2] = u0 - u2;                  Xi[2] = -(u4 - u6);
    Xr[3] = u1 - C1F * (p - q);       Xi[3] = u3 - C1F * (p + q);
    Xr[4] = u0 + u2 - u4 - u6;        Xi[4] = 0.f;
}

__device__ __forceinline__ void irfft8(const float Xr[5], const float Xi[5], float y[8]) {
    float A = Xr[0], B = Xr[4];
    float cr = Xr[1], ci = Xi[1], dr = Xr[2], di = Xi[2], er = Xr[3], ei = Xi[3];
    float abp = A + B, abm = A - B;
    float ccm = S2F * (cr - ci), ccp = S2F * (cr + ci);
    float eep = S2F * (er + ei), eem = S2F * (er - ei);
    float dr2 = 2.f * dr, di2 = 2.f * di;
    float cep = 2.f * (cr + er);
    float ci2 = 2.f * ci, ei2 = 2.f * ei;
    y[0] = abp + cep + dr2;
    y[1] = abm + ccm - di2 - eep;
    y[2] = abp - dr2 - ci2 + ei2;
    y[3] = abm - ccp + di2 + eem;
    y[4] = abp - cep + dr2;
    y[5] = abm - ccm - di2 + eep;
    y[6] = abp - dr2 + ci2 - ei2;
    y[7] = abm + ccp + di2 - eem;
}

__device__ __forceinline__ void cfwd(float& zr, float& zi, int r) {
    float or_ = __shfl_xor(zr, 4), oi_ = __shfl_xor(zi, 4);
    if (r < 4) { zr += or_; zi += oi_; }
    else {
        float tr = or_ - zr, ti = oi_ - zi;
        int m = r & 3;
        if (m == 0)      { zr = tr;              zi = ti; }
        else if (m == 1) { zr = C1F * (tr + ti); zi = C1F * (ti - tr); }
        else if (m == 2) { zr = ti;              zi = -tr; }
        else             { zr = C1F * (ti - tr); zi = -C1F * (tr + ti); }
    }
    or_ = __shfl_xor(zr, 2); oi_ = __shfl_xor(zi, 2);
    if ((r & 2) == 0) { zr += or_; zi += oi_; }
    else {
        float tr = or_ - zr, ti = oi_ - zi;
        if (r & 1) { zr = ti; zi = -tr; } else { zr = tr; zi = ti; }
    }
    or_ = __shfl_xor(zr, 1); oi_ = __shfl_xor(zi, 1);
    if ((r & 1) == 0) { zr += or_; zi += oi_; }
    else { zr = or_ - zr; zi = oi_ - zi; }
}

__device__ __forceinline__ void cinv(float& zr, float& zi, int r) {
    float or_ = __shfl_xor(zr, 1), oi_ = __shfl_xor(zi, 1);
    if ((r & 1) == 0) { zr += or_; zi += oi_; }
    else { zr = or_ - zr; zi = oi_ - zi; }
    or_ = __shfl_xor(zr, 2); oi_ = __shfl_xor(zi, 2);
    if ((r & 2) == 0) {
        if (r & 1) { zr -= oi_; zi += or_; }      // z += i*o
        else       { zr += or_; zi += oi_; }
    } else {
        if (r & 1) { float nr = or_ + zi, ni = oi_ - zr; zr = nr; zi = ni; } // z = o - i*z
        else       { zr = or_ - zr; zi = oi_ - zi; }
    }
    or_ = __shfl_xor(zr, 4); oi_ = __shfl_xor(zi, 4);
    int m = r & 3;
    if (r < 4) {   // z += w*o, w = e^{+i pi m/4}
        if (m == 0)      { zr += or_;                zi += oi_; }
        else if (m == 1) { zr += C1F * (or_ - oi_);  zi += C1F * (or_ + oi_); }
        else if (m == 2) { zr -= oi_;                zi += or_; }
        else             { zr += C1F * (-or_ - oi_); zi += C1F * (or_ - oi_); }
    } else {       // z = o - w*z
        float wr, wi;
        if (m == 0)      { wr = zr;                 wi = zi; }
        else if (m == 1) { wr = C1F * (zr - zi);    wi = C1F * (zr + zi); }
        else if (m == 2) { wr = -zi;                wi = zr; }
        else             { wr = C1F * (-zr - zi);   wi = C1F * (zr - zi); }
        zr = or_ - wr; zi = oi_ - wi;
    }
}

// ---------------- fused depthwise 3x3 + FFT attention (one chunk, one batch) ----------------
// grid (32, 19): x=strip ph, y=triplet channel cc. Handles global channels
// {c, 76+c, 152+c, 228+c} with c = tt19+cc. dw for q/k/v computed in FFT thread
// layout from LDS tile; vv dw'd in column layout and written directly.
__global__ __launch_bounds__(256) void k_dwfft(const float* __restrict__ chunk, // [4][19][HWSZ]
                                               const float* __restrict__ wdw,   // [304][9]
                                               float* __restrict__ hdwb,        // [304][65536]
                                               const float* __restrict__ fft_param,
                                               int tt19) {
    int ph = blockIdx.x, cc = blockIdx.y;
    int c = tt19 + cc;                                  // global q-channel 0..75
    int t = threadIdx.x;
    int p = t >> 3, r = t & 7;                          // patch in strip, row in patch
    int br = ((r & 1) << 2) | (r & 2) | (r >> 2);       // bitrev3(r)
    int r0 = ph * 8;

    __shared__ float tile[10 * 257];                    // rows r0-1..r0+8, stride 257 (bank-friendly)

    float Qr[5], Qi[5], Kr[5], Ki[5], Vr[5], Vi[5];

    for (int g = 0; g < 4; g++) {
        if (g) __syncthreads();                         // protect tile reuse
        const float* in = chunk + (size_t)(g * 19 + cc) * HWSZ;
        for (int i = t; i < 2560; i += 256) {
            int rr = i >> 8, col = i & 255;
            int gr = r0 - 1 + rr;
            tile[rr * 257 + col] = (gr >= 0 && gr < 256) ? in[gr * 256 + col] : 0.f;
        }
        __syncthreads();
        float w[9];
#pragma unroll
        for (int i = 0; i < 9; i++) w[i] = wdw[(76 * g + c) * 9 + i];   // uniform -> s_load

        if (g < 3) {
            // dw in FFT layout: thread (p,r) computes hdw row r, cols p*8..p*8+7
            float acc[8];
#pragma unroll
            for (int j = 0; j < 8; j++) acc[j] = 0.f;
#pragma unroll
            for (int rr = 0; rr < 3; rr++) {
                float v[10];
                int base = (r + rr) * 257 + p * 8;
                v[0] = (p > 0) ? tile[base - 1] : 0.f;
#pragma unroll
                for (int j = 0; j < 8; j++) v[j + 1] = tile[base + j];
                v[9] = (p < 31) ? tile[base + 8] : 0.f;
#pragma unroll
                for (int j = 0; j < 8; j++)
                    acc[j] += w[rr * 3 + 0] * v[j] + w[rr * 3 + 1] * v[j + 1] + w[rr * 3 + 2] * v[j + 2];
            }
            if (g == 0)      rfft8(acc, Qr, Qi);
            else if (g == 1) rfft8(acc, Kr, Ki);
            else             rfft8(acc, Vr, Vi);
        } else {
            // vv: dw in column layout, direct global store (coalesced per row)
            float cl[10], cm[10], cr_[10];
#pragma unroll
            for (int rr = 0; rr < 10; rr++) {
                cm[rr]  = tile[rr * 257 + t];
                cl[rr]  = (t > 0)   ? tile[rr * 257 + t - 1] : 0.f;
                cr_[rr] = (t < 255) ? tile[rr * 257 + t + 1] : 0.f;
            }
            float* out = hdwb + (size_t)(228 + c) * HWSZ + (size_t)r0 * 256 + t;
#pragma unroll
            for (int rr = 0; rr < 8; rr++) {
                float s = cl[rr] * w[0] + cm[rr] * w[1] + cr_[rr] * w[2]
                        + cl[rr + 1] * w[3] + cm[rr + 1] * w[4] + cr_[rr + 1] * w[5]
                        + cl[rr + 2] * w[6] + cm[rr + 2] * w[7] + cr_[rr + 2] * w[8];
                out[(size_t)rr * 256] = s;
            }
        }
    }

    // column FFTs (cross-lane over r)
#pragma unroll
    for (int v = 0; v < 5; v++) { cfwd(Qr[v], Qi[v], r); cfwd(Kr[v], Ki[v], r); cfwd(Vr[v], Vi[v], r); }

    const float inv64 = 0.015625f;
#pragma unroll
    for (int v = 0; v < 5; v++) {
        float pf = fft_param[(c * 8 + br) * 5 + v];
        float vr = Vr[v] * pf, vi = Vi[v] * pf;
        float qr = Qr[v], qi = Qi[v], kr = Kr[v], ki = Ki[v];
        float cr = qr * kr + qi * ki;          // qf * conj(kf)
        float ci = qi * kr - qr * ki;
        float m2q = cr * cr + ci * ci, m2v = vr * vr + vi * vi;
        float rq = rsqrtf(fmaxf(m2q, 1e-38f));
        float rv = rsqrtf(fmaxf(m2v, 1e-38f));
        float s  = sqrtf(m2v) * rq * inv64;    // |vf|/|qck| / 64
        float tt = sqrtf(m2q) * rv * inv64;    // |qck|/|vf| / 64
        Qr[v] = cr * s;      Qi[v] = ci * s;       // out1 = |vf| * unit(qck)
        Vr[v] = vr * tt;     Vi[v] = vi * tt;      // out2 = |qck| * unit(vf)
        Kr[v] = cr * inv64;  Ki[v] = ci * inv64;   // out3 = qck
    }

#pragma unroll
    for (int v = 0; v < 5; v++) { cinv(Qr[v], Qi[v], r); cinv(Vr[v], Vi[v], r); cinv(Kr[v], Ki[v], r); }

    size_t obase = (size_t)c * HWSZ + (size_t)(r0 + r) * 256 + p * 8;
    float y[8];
    irfft8(Qr, Qi, y);  // out1 -> q region
    { float4 f0 = {y[0],y[1],y[2],y[3]}, f1 = {y[4],y[5],y[6],y[7]};
      *(float4*)(hdwb + obase) = f0; *(float4*)(hdwb + obase + 4) = f1; }
    irfft8(Vr, Vi, y);  // out2 -> k region
    { float4 f0 = {y[0],y[1],y[2],y[3]}, f1 = {y[4],y[5],y[6],y[7]};
      *(float4*)(hdwb + obase + (size_t)76 * HWSZ) = f0;
      *(float4*)(hdwb + obase + (size_t)76 * HWSZ + 4) = f1; }
    irfft8(Kr, Ki, y);  // out3 -> v region
    { float4 f0 = {y[0],y[1],y[2],y[3]}, f1 = {y[4],y[5],y[6],y[7]};
      *(float4*)(hdwb + obase + (size_t)152 * HWSZ) = f0;
      *(float4*)(hdwb + obase + (size_t)152 * HWSZ + 4) = f1; }
}

// ---------------- layernorm + gate + final projection (one batch) ----------------
// 512 threads = 8 waves; lane owns 4 px (float4); wave w -> outputs [8w, 8w+8).
__global__ __launch_bounds__(512) void k_outb(const float* __restrict__ hdwb,
                                              const float* __restrict__ wt_p, // [c=228][o=64]
                                              const float* __restrict__ ln1w, const float* __restrict__ ln1b,
                                              const float* __restrict__ ln2w, const float* __restrict__ ln2b,
                                              const float* __restrict__ ln3w, const float* __restrict__ ln3b,
                                              float* __restrict__ outb) {
    int lane = threadIdx.x & 63;
    int w = threadIdx.x >> 6;                 // wave id 0..7
    int px = blockIdx.x * 256 + lane * 4;     // 4 pixels per lane
    const float* hb = hdwb + px;

    // LN stats: wave w sums channels c = w, w+8, ... for each of the 3 groups
    float4 s1 = f4(0), q1 = f4(0), s2 = f4(0), q2 = f4(0), s3 = f4(0), q3 = f4(0);
    for (int c = w; c < 76; c += 8) {
        float4 v1 = *(const float4*)(hb + (size_t)c * HWSZ);
        float4 v2 = *(const float4*)(hb + (size_t)(76 + c) * HWSZ);
        float4 v3 = *(const float4*)(hb + (size_t)(152 + c) * HWSZ);
        s1 += v1; q1 += v1 * v1;
        s2 += v2; q2 += v2 * v2;
        s3 += v3; q3 += v3 * v3;
    }
    __shared__ float4 sred[6][8][64];
    sred[0][w][lane] = s1; sred[1][w][lane] = q1;
    sred[2][w][lane] = s2; sred[3][w][lane] = q2;
    sred[4][w][lane] = s3; sred[5][w][lane] = q3;
    __syncthreads();
    s1 = f4(0); q1 = f4(0); s2 = f4(0); q2 = f4(0); s3 = f4(0); q3 = f4(0);
#pragma unroll
    for (int k = 0; k < 8; k++) {
        s1 += sred[0][k][lane]; q1 += sred[1][k][lane];
        s2 += sred[2][k][lane]; q2 += sred[3][k][lane];
        s3 += sred[4][k][lane]; q3 += sred[5][k][lane];
    }

    const float4 invE = f4(1.f / 76.f);
    float4 m1 = s1 * invE, m2 = s2 * invE, m3 = s3 * invE;
    float4 vr1 = q1 * invE - m1 * m1, vr2 = q2 * invE - m2 * m2, vr3 = q3 * invE - m3 * m3;
    float4 r1, r2, r3;
    r1.x = rsqrtf(fmaxf(vr1.x, 0.f) + 1e-5f); r1.y = rsqrtf(fmaxf(vr1.y, 0.f) + 1e-5f);
    r1.z = rsqrtf(fmaxf(vr1.z, 0.f) + 1e-5f); r1.w = rsqrtf(fmaxf(vr1.w, 0.f) + 1e-5f);
    r2.x = rsqrtf(fmaxf(vr2.x, 0.f) + 1e-5f); r2.y = rsqrtf(fmaxf(vr2.y, 0.f) + 1e-5f);
    r2.z = rsqrtf(fmaxf(vr2.z, 0.f) + 1e-5f); r2.w = rsqrtf(fmaxf(vr2.w, 0.f) + 1e-5f);
    r3.x = rsqrtf(fmaxf(vr3.x, 0.f) + 1e-5f); r3.y = rsqrtf(fmaxf(vr3.y, 0.f) + 1e-5f);
    r3.z = rsqrtf(fmaxf(vr3.z, 0.f) + 1e-5f); r3.w = rsqrtf(fmaxf(vr3.w, 0.f) + 1e-5f);

    int o0 = w * 8;
    float4 acc[8];
#pragma unroll
    for (int i = 0; i < 8; i++) acc[i] = f4(0);
    for (int c = 0; c < 76; c++) {
        float4 vv = *(const float4*)(hb + (size_t)(228 + c) * HWSZ);
        float4 v1 = ((*(const float4*)(hb + (size_t)c * HWSZ)         - m1) * r1 * f4(ln1w[c]) + f4(ln1b[c])) * vv;
        float4 v2 = ((*(const float4*)(hb + (size_t)(76 + c) * HWSZ)  - m2) * r2 * f4(ln2w[c]) + f4(ln2b[c])) * vv;
        float4 v3 = ((*(const float4*)(hb + (size_t)(152 + c) * HWSZ) - m3) * r3 * f4(ln3w[c]) + f4(ln3b[c])) * vv;
        const float* w1 = wt_p + c * 64 + o0;            // uniform -> s_load
        const float* w2 = wt_p + (76 + c) * 64 + o0;
        const float* w3 = wt_p + (152 + c) * 64 + o0;
#pragma unroll
        for (int i = 0; i < 8; i++)
            acc[i] += v1 * f4(w1[i]) + v2 * f4(w2[i]) + v3 * f4(w3[i]);
    }
#pragma unroll
    for (int i = 0; i < 8; i++)
        *(float4*)(outb + (size_t)(o0 + i) * HWSZ + px) = acc[i];
}

extern "C" void kernel_launch(void* const* d_in, const int* in_sizes, int n_in,
                              void* d_out, int out_size, void* d_ws, size_t ws_size,
                              hipStream_t stream) {
    const float* x    = (const float*)d_in[0];
    const float* wh   = (const float*)d_in[1];
    const float* wdw  = (const float*)d_in[2];
    const float* wp   = (const float*)d_in[3];
    const float* fftp = (const float*)d_in[4];
    const float* ln1w = (const float*)d_in[5];
    const float* ln1b = (const float*)d_in[6];
    const float* ln2w = (const float*)d_in[7];
    const float* ln2b = (const float*)d_in[8];
    const float* ln3w = (const float*)d_in[9];
    const float* ln3b = (const float*)d_in[10];
    float* out = (float*)d_out;
    float* ws  = (float*)d_ws;

    const size_t wbytes = (size_t)(WT_H_ELEMS + WT_P_ELEMS) * 4;
    const size_t need = (CH_ELEMS + (size_t)76 * HWSZ) * 4 + wbytes;   // ~99.8 MB
    if (ws_size < need) return;

    float* hdwb     = ws;                                   // [304][65536] per-batch
    float* chunkbuf = ws + CH_ELEMS;                        // [76][65536] triplet chunk
    float* wt_h     = chunkbuf + (size_t)76 * HWSZ;         // [64][304]
    float* wt_p     = wt_h + WT_H_ELEMS;                    // [228][64]

    hipLaunchKernelGGL(k_prep, dim3(134), dim3(256), 0, stream, wh, wp, wt_h, wt_p);

    for (int b = 0; b < 2; b++) {
        const float* xb = x + (size_t)b * 64 * HWSZ;
        for (int tt = 0; tt < 4; tt++) {
            hipLaunchKernelGGL(k_conv1c, dim3(256, 2), dim3(256), 0, stream,
                               xb, wt_h, chunkbuf, tt * 19);
            hipLaunchKernelGGL(k_dwfft, dim3(32, 19), dim3(256), 0, stream,
                               chunkbuf, wdw, hdwb, fftp, tt * 19);
        }
        hipLaunchKernelGGL(k_outb, dim3(256), dim3(512), 0, stream, hdwb, wt_p,
                           ln1w, ln1b, ln2w, ln2b, ln3w, ln3b,
                           out + (size_t)b * 64 * HWSZ);
    }
}

// Round 5
// 609.092 us; speedup vs baseline: 1.3259x; 1.3259x over previous
//
#include <hip/hip_runtime.h>
#include <cstdint>
#include <cstddef>

// Problem constants
constexpr int HWSZ = 65536;                       // 256*256 pixels per image
constexpr size_t CH_ELEMS = (size_t)304 * HWSZ;   // per-batch 304-channel buffer elems
constexpr int WT_H_ELEMS = 64 * 304;
constexpr int WT_P_ELEMS = 228 * 64;

// LDS tile pitch: 261 % 32 = 5 (odd) -> dw tap reads (4r+8p+...)%32 spread over
// all banks (conflict-free); vv column reads are 2-way (free). 260/256 gave 8-way.
constexpr int TP = 261;
constexpr int GS = 10 * TP;   // per-group tile size (2610)

#define C1F 0.70710678118654752f
#define S2F 1.41421356237309505f

// float4 / float2 helpers
__device__ __forceinline__ float4 f4(float v) { return make_float4(v, v, v, v); }
__device__ __forceinline__ float2 f2(float v) { return make_float2(v, v); }
__device__ __forceinline__ float2 operator+(float2 a, float2 b) { return make_float2(a.x+b.x, a.y+b.y); }
__device__ __forceinline__ float2 operator-(float2 a, float2 b) { return make_float2(a.x-b.x, a.y-b.y); }
__device__ __forceinline__ float2 operator*(float2 a, float2 b) { return make_float2(a.x*b.x, a.y*b.y); }
__device__ __forceinline__ float2& operator+=(float2& a, float2 b) { a.x+=b.x; a.y+=b.y; return a; }

// ---------------- prep: transpose weights for scalar-load GEMMs ----------------
__global__ __launch_bounds__(256) void k_prep(const float* __restrict__ wh,
                                              const float* __restrict__ wp,
                                              float* __restrict__ wt_h,
                                              float* __restrict__ wt_p) {
    int i = blockIdx.x * 256 + threadIdx.x;
    if (i < 64 * 304) {            // wh is [o=304][k=64] -> wt_h[k][o]
        int o = i / 64, k = i % 64;
        wt_h[k * 304 + o] = wh[i];
    }
    int j = i - 64 * 304;
    if (j >= 0 && j < 64 * 228) {  // wp is [o=64][c=228] -> wt_p[cc][o]
        int o = j / 228, cc = j % 228;
        wt_p[cc * 64 + o] = wp[j];
    }
}

// ---------------- 1x1 conv (one batch), R3-verified shape: grid (256, 8) ----------------
__global__ __launch_bounds__(256) void k_conv1(const float* __restrict__ xb,   // [64][65536]
                                               const float* __restrict__ wt,   // [k=64][o=304]
                                               float* __restrict__ hidden) {   // [304][65536]
    int sp = blockIdx.x * 256 + threadIdx.x;   // 0..65535
    float xv[64];
#pragma unroll
    for (int k = 0; k < 64; k++) xv[k] = xb[(size_t)k * HWSZ + sp];
    for (int h = 0; h < 2; h++) {
        int gbase = blockIdx.y * 38 + h * 19;      // out-channel base
        float acc[19];
#pragma unroll
        for (int i = 0; i < 19; i++) acc[i] = 0.f;
#pragma unroll
        for (int k = 0; k < 64; k++) {
            float xs = xv[k];
            const float* wrow = wt + k * 304 + gbase;   // uniform -> s_load
#pragma unroll
            for (int i = 0; i < 19; i++) acc[i] = fmaf(xs, wrow[i], acc[i]);
        }
#pragma unroll
        for (int i = 0; i < 19; i++) hidden[(size_t)(gbase + i) * HWSZ + sp] = acc[i];
    }
}

// ---------------- small FFT helpers (verified R2-R4) ----------------
__device__ __forceinline__ void rfft8(const float a[8], float Xr[5], float Xi[5]) {
    float u0 = a[0] + a[4], u1 = a[0] - a[4];
    float u2 = a[2] + a[6], u3 = a[2] - a[6];
    float u4 = a[1] + a[5], p  = a[1] - a[5];
    float u6 = a[3] + a[7], q  = a[3] - a[7];
    Xr[0] = u0 + u2 + u4 + u6;        Xi[0] = 0.f;
    Xr[1] = u1 + C1F * (p - q);       Xi[1] = -u3 - C1F * (p + q);
    Xr[2] = u0 - u2;                  Xi[2] = -(u4 - u6);
    Xr[3] = u1 - C1F * (p - q);       Xi[3] = u3 - C1F * (p + q);
    Xr[4] = u0 + u2 - u4 - u6;        Xi[4] = 0.f;
}

__device__ __forceinline__ void irfft8(const float Xr[5], const float Xi[5], float y[8]) {
    float A = Xr[0], B = Xr[4];
    float cr = Xr[1], ci = Xi[1], dr = Xr[2], di = Xi[2], er = Xr[3], ei = Xi[3];
    float abp = A + B, abm = A - B;
    float ccm = S2F * (cr - ci), ccp = S2F * (cr + ci);
    float eep = S2F * (er + ei), eem = S2F * (er - ei);
    float dr2 = 2.f * dr, di2 = 2.f * di;
    float cep = 2.f * (cr + er);
    float ci2 = 2.f * ci, ei2 = 2.f * ei;
    y[0] = abp + cep + dr2;
    y[1] = abm + ccm - di2 - eep;
    y[2] = abp - dr2 - ci2 + ei2;
    y[3] = abm - ccp + di2 + eem;
    y[4] = abp - cep + dr2;
    y[5] = abm - ccm - di2 + eep;
    y[6] = abp - dr2 + ci2 - ei2;
    y[7] = abm + ccp + di2 - eem;
}

__device__ __forceinline__ void cfwd(float& zr, float& zi, int r) {
    float or_ = __shfl_xor(zr, 4), oi_ = __shfl_xor(zi, 4);
    if (r < 4) { zr += or_; zi += oi_; }
    else {
        float tr = or_ - zr, ti = oi_ - zi;
        int m = r & 3;
        if (m == 0)      { zr = tr;              zi = ti; }
        else if (m == 1) { zr = C1F * (tr + ti); zi = C1F * (ti - tr); }
        else if (m == 2) { zr = ti;              zi = -tr; }
        else             { zr = C1F * (ti - tr); zi = -C1F * (tr + ti); }
    }
    or_ = __shfl_xor(zr, 2); oi_ = __shfl_xor(zi, 2);
    if ((r & 2) == 0) { zr += or_; zi += oi_; }
    else {
        float tr = or_ - zr, ti = oi_ - zi;
        if (r & 1) { zr = ti; zi = -tr; } else { zr = tr; zi = ti; }
    }
    or_ = __shfl_xor(zr, 1); oi_ = __shfl_xor(zi, 1);
    if ((r & 1) == 0) { zr += or_; zi += oi_; }
    else { zr = or_ - zr; zi = oi_ - zi; }
}

__device__ __forceinline__ void cinv(float& zr, float& zi, int r) {
    float or_ = __shfl_xor(zr, 1), oi_ = __shfl_xor(zi, 1);
    if ((r & 1) == 0) { zr += or_; zi += oi_; }
    else { zr = or_ - zr; zi = oi_ - zi; }
    or_ = __shfl_xor(zr, 2); oi_ = __shfl_xor(zi, 2);
    if ((r & 2) == 0) {
        if (r & 1) { zr -= oi_; zi += or_; }      // z += i*o
        else       { zr += or_; zi += oi_; }
    } else {
        if (r & 1) { float nr = or_ + zi, ni = oi_ - zr; zr = nr; zi = ni; } // z = o - i*z
        else       { zr = or_ - zr; zi = oi_ - zi; }
    }
    or_ = __shfl_xor(zr, 4); oi_ = __shfl_xor(zi, 4);
    int m = r & 3;
    if (r < 4) {   // z += w*o, w = e^{+i pi m/4}
        if (m == 0)      { zr += or_;                zi += oi_; }
        else if (m == 1) { zr += C1F * (or_ - oi_);  zi += C1F * (or_ + oi_); }
        else if (m == 2) { zr -= oi_;                zi += or_; }
        else             { zr += C1F * (-or_ - oi_); zi += C1F * (or_ - oi_); }
    } else {       // z = o - w*z
        float wr, wi;
        if (m == 0)      { wr = zr;                 wi = zi; }
        else if (m == 1) { wr = C1F * (zr - zi);    wi = C1F * (zr + zi); }
        else if (m == 2) { wr = -zi;                wi = zr; }
        else             { wr = C1F * (-zr - zi);   wi = C1F * (zr - zi); }
        zr = or_ - wr; zi = oi_ - wi;
    }
}

// ---------------- fused depthwise 3x3 + FFT attention (one batch, full width) ----------------
// grid (32, 76): x=strip ph, y=triplet channel c. Stages all 4 group tiles
// (q,k,v,vv for channels {c,76+c,152+c,228+c}) in one pass, single barrier.
__global__ __launch_bounds__(256) void k_dwfft(const float* __restrict__ hidden, // [304][65536]
                                               const float* __restrict__ wdw,    // [304][9]
                                               float* __restrict__ hdwb,         // [304][65536]
                                               const float* __restrict__ fft_param) {
    int ph = blockIdx.x, c = blockIdx.y;
    int t = threadIdx.x;
    int p = t >> 3, r = t & 7;                          // patch in strip, row in patch
    int br = ((r & 1) << 2) | (r & 2) | (r >> 2);       // bitrev3(r)
    int r0 = ph * 8;

    __shared__ float tile[4 * GS];                      // 4 groups x 10 rows x pitch 261

    // ---- stage: 2560 float4 slots, idx = j*256 + t (coalesced 1KB/wave) ----
#pragma unroll
    for (int j = 0; j < 10; j++) {
        int idx = j * 256 + t;
        int g = idx / 640;                   // const-divisor -> magic mul
        int rem = idx - g * 640;
        int rr = rem >> 6, c4 = rem & 63;
        int gr = r0 - 1 + rr;
        float4 val = f4(0.f);
        if (gr >= 0 && gr < 256)
            val = *(const float4*)(hidden + (size_t)(g * 76 + c) * HWSZ + gr * 256 + c4 * 4);
        float* d = tile + g * GS + rr * TP + c4 * 4;
        d[0] = val.x; d[1] = val.y; d[2] = val.z; d[3] = val.w;
    }
    __syncthreads();

    float Qr[5], Qi[5], Kr[5], Ki[5], Vr[5], Vi[5];

    // ---- q/k/v: dw 3x3 in FFT thread layout + row rfft8 ----
    for (int g = 0; g < 3; g++) {
        float w[9];
#pragma unroll
        for (int i = 0; i < 9; i++) w[i] = wdw[(76 * g + c) * 9 + i];   // uniform
        float acc[8];
#pragma unroll
        for (int j = 0; j < 8; j++) acc[j] = 0.f;
#pragma unroll
        for (int rr = 0; rr < 3; rr++) {
            float v[10];
            int base = g * GS + (r + rr) * TP + p * 8;
            v[0] = (p > 0) ? tile[base - 1] : 0.f;
#pragma unroll
            for (int j = 0; j < 8; j++) v[j + 1] = tile[base + j];
            v[9] = (p < 31) ? tile[base + 8] : 0.f;
#pragma unroll
            for (int j = 0; j < 8; j++)
                acc[j] += w[rr * 3 + 0] * v[j] + w[rr * 3 + 1] * v[j + 1] + w[rr * 3 + 2] * v[j + 2];
        }
        if (g == 0)      rfft8(acc, Qr, Qi);
        else if (g == 1) rfft8(acc, Kr, Ki);
        else             rfft8(acc, Vr, Vi);
    }

    // ---- vv: dw 3x3 in column layout, direct store ----
    {
        float w[9];
#pragma unroll
        for (int i = 0; i < 9; i++) w[i] = wdw[(228 + c) * 9 + i];
        float cl[10], cm[10], cr_[10];
#pragma unroll
        for (int rr = 0; rr < 10; rr++) {
            int base = 3 * GS + rr * TP + t;
            cm[rr]  = tile[base];
            cl[rr]  = (t > 0)   ? tile[base - 1] : 0.f;
            cr_[rr] = (t < 255) ? tile[base + 1] : 0.f;
        }
        float* outp = hdwb + (size_t)(228 + c) * HWSZ + (size_t)r0 * 256 + t;
#pragma unroll
        for (int rr = 0; rr < 8; rr++) {
            float s = cl[rr] * w[0] + cm[rr] * w[1] + cr_[rr] * w[2]
                    + cl[rr + 1] * w[3] + cm[rr + 1] * w[4] + cr_[rr + 1] * w[5]
                    + cl[rr + 2] * w[6] + cm[rr + 2] * w[7] + cr_[rr + 2] * w[8];
            outp[(size_t)rr * 256] = s;
        }
    }

    // ---- column FFTs, pointwise phase/magnitude mix, inverse ----
#pragma unroll
    for (int v = 0; v < 5; v++) { cfwd(Qr[v], Qi[v], r); cfwd(Kr[v], Ki[v], r); cfwd(Vr[v], Vi[v], r); }

    const float inv64 = 0.015625f;
#pragma unroll
    for (int v = 0; v < 5; v++) {
        float pf = fft_param[(c * 8 + br) * 5 + v];
        float vr = Vr[v] * pf, vi = Vi[v] * pf;
        float qr = Qr[v], qi = Qi[v], kr = Kr[v], ki = Ki[v];
        float cr = qr * kr + qi * ki;          // qf * conj(kf)
        float ci = qi * kr - qr * ki;
        float m2q = cr * cr + ci * ci, m2v = vr * vr + vi * vi;
        float rq = rsqrtf(fmaxf(m2q, 1e-38f));
        float rv = rsqrtf(fmaxf(m2v, 1e-38f));
        float s  = sqrtf(m2v) * rq * inv64;    // |vf|/|qck| / 64
        float tt = sqrtf(m2q) * rv * inv64;    // |qck|/|vf| / 64
        Qr[v] = cr * s;      Qi[v] = ci * s;       // out1 = |vf| * unit(qck)
        Vr[v] = vr * tt;     Vi[v] = vi * tt;      // out2 = |qck| * unit(vf)
        Kr[v] = cr * inv64;  Ki[v] = ci * inv64;   // out3 = qck
    }

#pragma unroll
    for (int v = 0; v < 5; v++) { cinv(Qr[v], Qi[v], r); cinv(Vr[v], Vi[v], r); cinv(Kr[v], Ki[v], r); }

    size_t obase = (size_t)c * HWSZ + (size_t)(r0 + r) * 256 + p * 8;
    float y[8];
    irfft8(Qr, Qi, y);  // out1 -> q region
    { float4 f0 = {y[0],y[1],y[2],y[3]}, f1 = {y[4],y[5],y[6],y[7]};
      *(float4*)(hdwb + obase) = f0; *(float4*)(hdwb + obase + 4) = f1; }
    irfft8(Vr, Vi, y);  // out2 -> k region
    { float4 f0 = {y[0],y[1],y[2],y[3]}, f1 = {y[4],y[5],y[6],y[7]};
      *(float4*)(hdwb + obase + (size_t)76 * HWSZ) = f0;
      *(float4*)(hdwb + obase + (size_t)76 * HWSZ + 4) = f1; }
    irfft8(Kr, Ki, y);  // out3 -> v region
    { float4 f0 = {y[0],y[1],y[2],y[3]}, f1 = {y[4],y[5],y[6],y[7]};
      *(float4*)(hdwb + obase + (size_t)152 * HWSZ) = f0;
      *(float4*)(hdwb + obase + (size_t)152 * HWSZ + 4) = f1; }
}

// ---------------- layernorm + gate + final projection (one batch) ----------------
// 512 threads = 8 waves; lane owns 2 px (float2); wave w -> outputs [8w, 8w+8).
// grid 512 blocks -> 2 blocks/CU -> 16 waves/CU (R4 grid 256 was occupancy-capped).
__global__ __launch_bounds__(512) void k_outb(const float* __restrict__ hdwb,
                                              const float* __restrict__ wt_p, // [c=228][o=64]
                                              const float* __restrict__ ln1w, const float* __restrict__ ln1b,
                                              const float* __restrict__ ln2w, const float* __restrict__ ln2b,
                                              const float* __restrict__ ln3w, const float* __restrict__ ln3b,
                                              float* __restrict__ outb) {
    int lane = threadIdx.x & 63;
    int w = threadIdx.x >> 6;                 // wave id 0..7
    int px = blockIdx.x * 128 + lane * 2;     // 2 pixels per lane
    const float* hb = hdwb + px;

    // LN stats: wave w sums channels c = w, w+8, ...
    float2 s1 = f2(0), q1 = f2(0), s2 = f2(0), q2 = f2(0), s3 = f2(0), q3 = f2(0);
    for (int c = w; c < 76; c += 8) {
        float2 v1 = *(const float2*)(hb + (size_t)c * HWSZ);
        float2 v2 = *(const float2*)(hb + (size_t)(76 + c) * HWSZ);
        float2 v3 = *(const float2*)(hb + (size_t)(152 + c) * HWSZ);
        s1 += v1; q1 += v1 * v1;
        s2 += v2; q2 += v2 * v2;
        s3 += v3; q3 += v3 * v3;
    }
    __shared__ float2 sred[6][8][64];
    sred[0][w][lane] = s1; sred[1][w][lane] = q1;
    sred[2][w][lane] = s2; sred[3][w][lane] = q2;
    sred[4][w][lane] = s3; sred[5][w][lane] = q3;
    __syncthreads();
    s1 = f2(0); q1 = f2(0); s2 = f2(0); q2 = f2(0); s3 = f2(0); q3 = f2(0);
#pragma unroll
    for (int k = 0; k < 8; k++) {
        s1 += sred[0][k][lane]; q1 += sred[1][k][lane];
        s2 += sred[2][k][lane]; q2 += sred[3][k][lane];
        s3 += sred[4][k][lane]; q3 += sred[5][k][lane];
    }

    const float2 invE = f2(1.f / 76.f);
    float2 m1 = s1 * invE, m2 = s2 * invE, m3 = s3 * invE;
    float2 vr1 = q1 * invE - m1 * m1, vr2 = q2 * invE - m2 * m2, vr3 = q3 * invE - m3 * m3;
    float2 r1, r2, r3;
    r1.x = rsqrtf(fmaxf(vr1.x, 0.f) + 1e-5f); r1.y = rsqrtf(fmaxf(vr1.y, 0.f) + 1e-5f);
    r2.x = rsqrtf(fmaxf(vr2.x, 0.f) + 1e-5f); r2.y = rsqrtf(fmaxf(vr2.y, 0.f) + 1e-5f);
    r3.x = rsqrtf(fmaxf(vr3.x, 0.f) + 1e-5f); r3.y = rsqrtf(fmaxf(vr3.y, 0.f) + 1e-5f);

    int o0 = w * 8;
    float2 acc[8];
#pragma unroll
    for (int i = 0; i < 8; i++) acc[i] = f2(0);
    for (int c = 0; c < 76; c++) {
        float2 vv = *(const float2*)(hb + (size_t)(228 + c) * HWSZ);
        float2 v1 = ((*(const float2*)(hb + (size_t)c * HWSZ)         - m1) * r1 * f2(ln1w[c]) + f2(ln1b[c])) * vv;
        float2 v2 = ((*(const float2*)(hb + (size_t)(76 + c) * HWSZ)  - m2) * r2 * f2(ln2w[c]) + f2(ln2b[c])) * vv;
        float2 v3 = ((*(const float2*)(hb + (size_t)(152 + c) * HWSZ) - m3) * r3 * f2(ln3w[c]) + f2(ln3b[c])) * vv;
        const float* w1 = wt_p + c * 64 + o0;            // uniform -> s_load
        const float* w2 = wt_p + (76 + c) * 64 + o0;
        const float* w3 = wt_p + (152 + c) * 64 + o0;
#pragma unroll
        for (int i = 0; i < 8; i++)
            acc[i] += v1 * f2(w1[i]) + v2 * f2(w2[i]) + v3 * f2(w3[i]);
    }
#pragma unroll
    for (int i = 0; i < 8; i++)
        *(float2*)(outb + (size_t)(o0 + i) * HWSZ + px) = acc[i];
}

extern "C" void kernel_launch(void* const* d_in, const int* in_sizes, int n_in,
                              void* d_out, int out_size, void* d_ws, size_t ws_size,
                              hipStream_t stream) {
    const float* x    = (const float*)d_in[0];
    const float* wh   = (const float*)d_in[1];
    const float* wdw  = (const float*)d_in[2];
    const float* wp   = (const float*)d_in[3];
    const float* fftp = (const float*)d_in[4];
    const float* ln1w = (const float*)d_in[5];
    const float* ln1b = (const float*)d_in[6];
    const float* ln2w = (const float*)d_in[7];
    const float* ln2b = (const float*)d_in[8];
    const float* ln3w = (const float*)d_in[9];
    const float* ln3b = (const float*)d_in[10];
    float* out = (float*)d_out;
    float* ws  = (float*)d_ws;

    const size_t wbytes = (size_t)(WT_H_ELEMS + WT_P_ELEMS) * 4;
    const size_t need = 2 * CH_ELEMS * 4 + wbytes;   // ~159.8 MB (R2/R3 confirmed available)
    if (ws_size < need) return;

    float* hidden = ws;                         // [304][65536] per-batch conv output
    float* hdwb   = ws + CH_ELEMS;              // [304][65536] dw+fft output
    float* wt_h   = ws + 2 * CH_ELEMS;          // [64][304]
    float* wt_p   = wt_h + WT_H_ELEMS;          // [228][64]

    hipLaunchKernelGGL(k_prep, dim3(134), dim3(256), 0, stream, wh, wp, wt_h, wt_p);

    for (int b = 0; b < 2; b++) {
        const float* xb = x + (size_t)b * 64 * HWSZ;
        hipLaunchKernelGGL(k_conv1, dim3(256, 8), dim3(256), 0, stream, xb, wt_h, hidden);
        hipLaunchKernelGGL(k_dwfft, dim3(32, 76), dim3(256), 0, stream, hidden, wdw, hdwb, fftp);
        hipLaunchKernelGGL(k_outb, dim3(512), dim3(512), 0, stream, hdwb, wt_p,
                           ln1w, ln1b, ln2w, ln2b, ln3w, ln3b,
                           out + (size_t)b * 64 * HWSZ);
    }
}

// Round 6
// 529.629 us; speedup vs baseline: 1.5248x; 1.1500x over previous
//
#include <hip/hip_runtime.h>
#include <cstdint>
#include <cstddef>

// Problem constants
constexpr int HWSZ = 65536;                       // 256*256 pixels per image
constexpr size_t CH_ELEMS = (size_t)304 * HWSZ;   // per-batch 304-channel buffer elems
constexpr int WT_H_ELEMS = 64 * 304;
constexpr int WT_P_ELEMS = 228 * 64;

// LDS tile pitch: 261 % 32 = 5 (odd) -> dw tap reads spread across banks.
constexpr int TP = 261;
constexpr int GS = 10 * TP;   // per-group tile size (2610)

#define C1F 0.70710678118654752f
#define S2F 1.41421356237309505f

// float4 helpers
__device__ __forceinline__ float4 f4(float v) { return make_float4(v, v, v, v); }
__device__ __forceinline__ float4 operator+(float4 a, float4 b) { return make_float4(a.x+b.x, a.y+b.y, a.z+b.z, a.w+b.w); }
__device__ __forceinline__ float4 operator-(float4 a, float4 b) { return make_float4(a.x-b.x, a.y-b.y, a.z-b.z, a.w-b.w); }
__device__ __forceinline__ float4 operator*(float4 a, float4 b) { return make_float4(a.x*b.x, a.y*b.y, a.z*b.z, a.w*b.w); }
__device__ __forceinline__ float4& operator+=(float4& a, float4 b) { a.x+=b.x; a.y+=b.y; a.z+=b.z; a.w+=b.w; return a; }

// ---------------- prep: transpose weights for scalar-load GEMMs ----------------
__global__ __launch_bounds__(256) void k_prep(const float* __restrict__ wh,
                                              const float* __restrict__ wp,
                                              float* __restrict__ wt_h,
                                              float* __restrict__ wt_p) {
    int i = blockIdx.x * 256 + threadIdx.x;
    if (i < 64 * 304) {            // wh is [o=304][k=64] -> wt_h[k][o]
        int o = i / 64, k = i % 64;
        wt_h[k * 304 + o] = wh[i];
    }
    int j = i - 64 * 304;
    if (j >= 0 && j < 64 * 228) {  // wp is [o=64][c=228] -> wt_p[cc][o]
        int o = j / 228, cc = j % 228;
        wt_p[cc * 64 + o] = wp[j];
    }
}

// ---------------- 1x1 conv (one batch), grid (256, 8) ----------------
__global__ __launch_bounds__(256) void k_conv1(const float* __restrict__ xb,   // [64][65536]
                                               const float* __restrict__ wt,   // [k=64][o=304]
                                               float* __restrict__ hidden) {   // [304][65536]
    int sp = blockIdx.x * 256 + threadIdx.x;   // 0..65535
    float xv[64];
#pragma unroll
    for (int k = 0; k < 64; k++) xv[k] = xb[(size_t)k * HWSZ + sp];
    for (int h = 0; h < 2; h++) {
        int gbase = blockIdx.y * 38 + h * 19;      // out-channel base
        float acc[19];
#pragma unroll
        for (int i = 0; i < 19; i++) acc[i] = 0.f;
#pragma unroll
        for (int k = 0; k < 64; k++) {
            float xs = xv[k];
            const float* wrow = wt + k * 304 + gbase;   // uniform -> s_load
#pragma unroll
            for (int i = 0; i < 19; i++) acc[i] = fmaf(xs, wrow[i], acc[i]);
        }
#pragma unroll
        for (int i = 0; i < 19; i++) hidden[(size_t)(gbase + i) * HWSZ + sp] = acc[i];
    }
}

// ---------------- small FFT helpers (rfft8/irfft8 verified R2-R5) ----------------
__device__ __forceinline__ void rfft8(const float a[8], float Xr[5], float Xi[5]) {
    float u0 = a[0] + a[4], u1 = a[0] - a[4];
    float u2 = a[2] + a[6], u3 = a[2] - a[6];
    float u4 = a[1] + a[5], p  = a[1] - a[5];
    float u6 = a[3] + a[7], q  = a[3] - a[7];
    Xr[0] = u0 + u2 + u4 + u6;        Xi[0] = 0.f;
    Xr[1] = u1 + C1F * (p - q);       Xi[1] = -u3 - C1F * (p + q);
    Xr[2] = u0 - u2;                  Xi[2] = -(u4 - u6);
    Xr[3] = u1 - C1F * (p - q);       Xi[3] = u3 - C1F * (p + q);
    Xr[4] = u0 + u2 - u4 - u6;        Xi[4] = 0.f;
}

__device__ __forceinline__ void irfft8(const float Xr[5], const float Xi[5], float y[8]) {
    float A = Xr[0], B = Xr[4];
    float cr = Xr[1], ci = Xi[1], dr = Xr[2], di = Xi[2], er = Xr[3], ei = Xi[3];
    float abp = A + B, abm = A - B;
    float ccm = S2F * (cr - ci), ccp = S2F * (cr + ci);
    float eep = S2F * (er + ei), eem = S2F * (er - ei);
    float dr2 = 2.f * dr, di2 = 2.f * di;
    float cep = 2.f * (cr + er);
    float ci2 = 2.f * ci, ei2 = 2.f * ei;
    y[0] = abp + cep + dr2;
    y[1] = abm + ccm - di2 - eep;
    y[2] = abp - dr2 - ci2 + ei2;
    y[3] = abm - ccp + di2 + eem;
    y[4] = abp - cep + dr2;
    y[5] = abm - ccm - di2 + eep;
    y[6] = abp - dr2 + ci2 - ei2;
    y[7] = abm + ccp + di2 - eem;
}

// Branch-free butterfly stage applied to all 15 (Q,K,V x 5 bins) values:
// z' = A (.) z + B (.) partner   (complex per-lane coefficients)
__device__ __forceinline__ void bf_stage(float zr[15], float zi[15], int mask,
                                         float Ar, float Ai, float Br, float Bi) {
#pragma unroll
    for (int j = 0; j < 15; j++) {
        float or_ = __shfl_xor(zr[j], mask);
        float oi_ = __shfl_xor(zi[j], mask);
        float nr = Ar * zr[j] - Ai * zi[j] + Br * or_ - Bi * oi_;
        float ni = Ar * zi[j] + Ai * zr[j] + Br * oi_ + Bi * or_;
        zr[j] = nr; zi[j] = ni;
    }
}

// DIF forward FFT-8 over lanes (output scrambled: lane r holds bin bitrev3(r)).
// Coefficients derived from the R2-verified branchy cfwd:
//  S1(mask4): lower A=B=1; upper A=-W, B=W, W=e^{-i pi m/4}, m=r&3
//  S2(mask2): lower A=B=1; upper A=-W, B=W, W=(r&1)?(0,-1):(1,0)
//  S3(mask1): even A=B=1; odd A=-1, B=1
__device__ __forceinline__ void cfwd15(float zr[15], float zi[15], int r) {
    int m = r & 3;
    float wr = (m == 0) ? 1.f : (m == 1) ? C1F : (m == 2) ? 0.f : -C1F;
    float wi = (m == 0) ? 0.f : (m == 1) ? -C1F : (m == 2) ? -1.f : -C1F;
    bool up = r >= 4;
    bf_stage(zr, zi, 4, up ? -wr : 1.f, up ? -wi : 0.f, up ? wr : 1.f, up ? wi : 0.f);
    bool u2 = (r & 2) != 0;
    float w2r = (r & 1) ? 0.f : 1.f, w2i = (r & 1) ? -1.f : 0.f;
    bf_stage(zr, zi, 2, u2 ? -w2r : 1.f, u2 ? -w2i : 0.f, u2 ? w2r : 1.f, u2 ? w2i : 0.f);
    bf_stage(zr, zi, 1, (r & 1) ? -1.f : 1.f, 0.f, 1.f, 0.f);
}

// DIT inverse FFT-8 (scrambled input -> natural order), from R2-verified cinv:
//  S1(mask1): even A=B=1; odd A=-1, B=1
//  S2(mask2): r&2==0: A=1, B=(r&1)?(0,1):(1,0); r&2: A=(r&1)?(0,-1):(-1,0), B=1
//  S3(mask4): W=e^{+i pi m/4}; r<4: A=1, B=W; r>=4: A=-W, B=1
__device__ __forceinline__ void cinv15(float zr[15], float zi[15], int r) {
    bf_stage(zr, zi, 1, (r & 1) ? -1.f : 1.f, 0.f, 1.f, 0.f);
    float a2r, a2i, b2r, b2i;
    if ((r & 2) == 0) { a2r = 1.f; a2i = 0.f; b2r = (r & 1) ? 0.f : 1.f; b2i = (r & 1) ? 1.f : 0.f; }
    else             { a2r = (r & 1) ? 0.f : -1.f; a2i = (r & 1) ? -1.f : 0.f; b2r = 1.f; b2i = 0.f; }
    bf_stage(zr, zi, 2, a2r, a2i, b2r, b2i);
    int m = r & 3;
    float wr = (m == 0) ? 1.f : (m == 1) ? C1F : (m == 2) ? 0.f : -C1F;
    float wi = (m == 0) ? 0.f : (m == 1) ? C1F : (m == 2) ? 1.f : C1F;
    bool up = r >= 4;
    bf_stage(zr, zi, 4, up ? -wr : 1.f, up ? -wi : 0.f, up ? 1.f : wr, up ? 0.f : wi);
}

// ---------------- fused depthwise 3x3 + FFT attention (one batch) ----------------
// grid (32, 76): x=strip ph, y=triplet channel c.
__global__ __launch_bounds__(256) void k_dwfft(const float* __restrict__ hidden, // [304][65536]
                                               const float* __restrict__ wdw,    // [304][9]
                                               float* __restrict__ hdwb,         // [304][65536]
                                               const float* __restrict__ fft_param) {
    int ph = blockIdx.x, c = blockIdx.y;
    int t = threadIdx.x;
    int p = t >> 3, r = t & 7;                          // patch in strip, row in patch
    int br = ((r & 1) << 2) | (r & 2) | (r >> 2);       // bitrev3(r)
    int r0 = ph * 8;

    __shared__ float tile[4 * GS];                      // 4 groups x 10 rows x pitch 261

    // ---- stage: 2560 float4 slots, coalesced ----
#pragma unroll
    for (int j = 0; j < 10; j++) {
        int idx = j * 256 + t;
        int g = idx / 640;
        int rem = idx - g * 640;
        int rr = rem >> 6, c4 = rem & 63;
        int gr = r0 - 1 + rr;
        float4 val = f4(0.f);
        if (gr >= 0 && gr < 256)
            val = *(const float4*)(hidden + (size_t)(g * 76 + c) * HWSZ + gr * 256 + c4 * 4);
        float* d = tile + g * GS + rr * TP + c4 * 4;
        d[0] = val.x; d[1] = val.y; d[2] = val.z; d[3] = val.w;
    }
    __syncthreads();

    // z-slots: 0..4 = Q/out1, 5..9 = K/out3, 10..14 = V/out2
    float zr[15], zi[15];

    // ---- q/k/v: dw 3x3 in FFT thread layout + row rfft8 ----
    for (int g = 0; g < 3; g++) {
        float w[9];
#pragma unroll
        for (int i = 0; i < 9; i++) w[i] = wdw[(76 * g + c) * 9 + i];   // uniform
        float acc[8];
#pragma unroll
        for (int j = 0; j < 8; j++) acc[j] = 0.f;
#pragma unroll
        for (int rr = 0; rr < 3; rr++) {
            float v[10];
            int base = g * GS + (r + rr) * TP + p * 8;
            v[0] = (p > 0) ? tile[base - 1] : 0.f;
#pragma unroll
            for (int j = 0; j < 8; j++) v[j + 1] = tile[base + j];
            v[9] = (p < 31) ? tile[base + 8] : 0.f;
#pragma unroll
            for (int j = 0; j < 8; j++)
                acc[j] += w[rr * 3 + 0] * v[j] + w[rr * 3 + 1] * v[j + 1] + w[rr * 3 + 2] * v[j + 2];
        }
        float Xr[5], Xi[5];
        rfft8(acc, Xr, Xi);
        int s0 = (g == 0) ? 0 : (g == 1) ? 5 : 10;
#pragma unroll
        for (int v = 0; v < 5; v++) { zr[s0 + v] = Xr[v]; zi[s0 + v] = Xi[v]; }
    }

    // ---- vv: dw 3x3 in column layout, direct store ----
    {
        float w[9];
#pragma unroll
        for (int i = 0; i < 9; i++) w[i] = wdw[(228 + c) * 9 + i];
        float cl[10], cm[10], cr_[10];
#pragma unroll
        for (int rr = 0; rr < 10; rr++) {
            int base = 3 * GS + rr * TP + t;
            cm[rr]  = tile[base];
            cl[rr]  = (t > 0)   ? tile[base - 1] : 0.f;
            cr_[rr] = (t < 255) ? tile[base + 1] : 0.f;
        }
        float* outp = hdwb + (size_t)(228 + c) * HWSZ + (size_t)r0 * 256 + t;
#pragma unroll
        for (int rr = 0; rr < 8; rr++) {
            float s = cl[rr] * w[0] + cm[rr] * w[1] + cr_[rr] * w[2]
                    + cl[rr + 1] * w[3] + cm[rr + 1] * w[4] + cr_[rr + 1] * w[5]
                    + cl[rr + 2] * w[6] + cm[rr + 2] * w[7] + cr_[rr + 2] * w[8];
            outp[(size_t)rr * 256] = s;
        }
    }

    // ---- column FFTs (branch-free), pointwise mix, inverse ----
    cfwd15(zr, zi, r);

    const float inv64 = 0.015625f;
#pragma unroll
    for (int v = 0; v < 5; v++) {
        float pf = fft_param[(c * 8 + br) * 5 + v];
        float vr = zr[10 + v] * pf, vi = zi[10 + v] * pf;
        float qr = zr[v], qi = zi[v], kr = zr[5 + v], ki = zi[5 + v];
        float cr = qr * kr + qi * ki;          // qf * conj(kf)
        float ci = qi * kr - qr * ki;
        float m2q = cr * cr + ci * ci, m2v = vr * vr + vi * vi;
        float rq = rsqrtf(fmaxf(m2q, 1e-38f));
        float rv = rsqrtf(fmaxf(m2v, 1e-38f));
        float s  = sqrtf(m2v) * rq * inv64;    // |vf|/|qck| / 64
        float tt = sqrtf(m2q) * rv * inv64;    // |qck|/|vf| / 64
        zr[v] = cr * s;           zi[v] = ci * s;          // out1
        zr[10 + v] = vr * tt;     zi[10 + v] = vi * tt;    // out2
        zr[5 + v] = cr * inv64;   zi[5 + v] = ci * inv64;  // out3
    }

    cinv15(zr, zi, r);

    size_t obase = (size_t)c * HWSZ + (size_t)(r0 + r) * 256 + p * 8;
    float Xr[5], Xi[5], y[8];
#pragma unroll
    for (int v = 0; v < 5; v++) { Xr[v] = zr[v]; Xi[v] = zi[v]; }
    irfft8(Xr, Xi, y);  // out1 -> q region
    { float4 f0 = {y[0],y[1],y[2],y[3]}, f1 = {y[4],y[5],y[6],y[7]};
      *(float4*)(hdwb + obase) = f0; *(float4*)(hdwb + obase + 4) = f1; }
#pragma unroll
    for (int v = 0; v < 5; v++) { Xr[v] = zr[10 + v]; Xi[v] = zi[10 + v]; }
    irfft8(Xr, Xi, y);  // out2 -> k region
    { float4 f0 = {y[0],y[1],y[2],y[3]}, f1 = {y[4],y[5],y[6],y[7]};
      *(float4*)(hdwb + obase + (size_t)76 * HWSZ) = f0;
      *(float4*)(hdwb + obase + (size_t)76 * HWSZ + 4) = f1; }
#pragma unroll
    for (int v = 0; v < 5; v++) { Xr[v] = zr[5 + v]; Xi[v] = zi[5 + v]; }
    irfft8(Xr, Xi, y);  // out3 -> v region
    { float4 f0 = {y[0],y[1],y[2],y[3]}, f1 = {y[4],y[5],y[6],y[7]};
      *(float4*)(hdwb + obase + (size_t)152 * HWSZ) = f0;
      *(float4*)(hdwb + obase + (size_t)152 * HWSZ + 4) = f1; }
}

// ---------------- layernorm + gate + final projection (one batch) ----------------
// R4-exact shape (512 thr, 4 px/lane float4, 256 blocks) + 2-deep c-pipeline.
__global__ __launch_bounds__(512) void k_outb(const float* __restrict__ hdwb,
                                              const float* __restrict__ wt_p, // [c=228][o=64]
                                              const float* __restrict__ ln1w, const float* __restrict__ ln1b,
                                              const float* __restrict__ ln2w, const float* __restrict__ ln2b,
                                              const float* __restrict__ ln3w, const float* __restrict__ ln3b,
                                              float* __restrict__ outb) {
    int lane = threadIdx.x & 63;
    int w = threadIdx.x >> 6;                 // wave id 0..7
    int px = blockIdx.x * 256 + lane * 4;     // 4 pixels per lane
    const float* hb = hdwb + px;

    float4 s1 = f4(0), q1 = f4(0), s2 = f4(0), q2 = f4(0), s3 = f4(0), q3 = f4(0);
    for (int c = w; c < 76; c += 8) {
        float4 v1 = *(const float4*)(hb + (size_t)c * HWSZ);
        float4 v2 = *(const float4*)(hb + (size_t)(76 + c) * HWSZ);
        float4 v3 = *(const float4*)(hb + (size_t)(152 + c) * HWSZ);
        s1 += v1; q1 += v1 * v1;
        s2 += v2; q2 += v2 * v2;
        s3 += v3; q3 += v3 * v3;
    }
    __shared__ float4 sred[6][8][64];
    sred[0][w][lane] = s1; sred[1][w][lane] = q1;
    sred[2][w][lane] = s2; sred[3][w][lane] = q2;
    sred[4][w][lane] = s3; sred[5][w][lane] = q3;
    __syncthreads();
    s1 = f4(0); q1 = f4(0); s2 = f4(0); q2 = f4(0); s3 = f4(0); q3 = f4(0);
#pragma unroll
    for (int k = 0; k < 8; k++) {
        s1 += sred[0][k][lane]; q1 += sred[1][k][lane];
        s2 += sred[2][k][lane]; q2 += sred[3][k][lane];
        s3 += sred[4][k][lane]; q3 += sred[5][k][lane];
    }

    const float4 invE = f4(1.f / 76.f);
    float4 m1 = s1 * invE, m2 = s2 * invE, m3 = s3 * invE;
    float4 vr1 = q1 * invE - m1 * m1, vr2 = q2 * invE - m2 * m2, vr3 = q3 * invE - m3 * m3;
    float4 r1, r2, r3;
    r1.x = rsqrtf(fmaxf(vr1.x, 0.f) + 1e-5f); r1.y = rsqrtf(fmaxf(vr1.y, 0.f) + 1e-5f);
    r1.z = rsqrtf(fmaxf(vr1.z, 0.f) + 1e-5f); r1.w = rsqrtf(fmaxf(vr1.w, 0.f) + 1e-5f);
    r2.x = rsqrtf(fmaxf(vr2.x, 0.f) + 1e-5f); r2.y = rsqrtf(fmaxf(vr2.y, 0.f) + 1e-5f);
    r2.z = rsqrtf(fmaxf(vr2.z, 0.f) + 1e-5f); r2.w = rsqrtf(fmaxf(vr2.w, 0.f) + 1e-5f);
    r3.x = rsqrtf(fmaxf(vr3.x, 0.f) + 1e-5f); r3.y = rsqrtf(fmaxf(vr3.y, 0.f) + 1e-5f);
    r3.z = rsqrtf(fmaxf(vr3.z, 0.f) + 1e-5f); r3.w = rsqrtf(fmaxf(vr3.w, 0.f) + 1e-5f);

    int o0 = w * 8;
    float4 acc[8];
#pragma unroll
    for (int i = 0; i < 8; i++) acc[i] = f4(0);

    // software pipeline: prefetch c+1 loads during c compute
    float4 pv = *(const float4*)(hb + (size_t)228 * HWSZ);
    float4 p1 = *(const float4*)(hb);
    float4 p2 = *(const float4*)(hb + (size_t)76 * HWSZ);
    float4 p3 = *(const float4*)(hb + (size_t)152 * HWSZ);
    for (int c = 0; c < 76; c++) {
        float4 vv = pv, l1 = p1, l2 = p2, l3 = p3;
        if (c < 75) {
            pv = *(const float4*)(hb + (size_t)(229 + c) * HWSZ);
            p1 = *(const float4*)(hb + (size_t)(1 + c) * HWSZ);
            p2 = *(const float4*)(hb + (size_t)(77 + c) * HWSZ);
            p3 = *(const float4*)(hb + (size_t)(153 + c) * HWSZ);
        }
        float4 v1 = ((l1 - m1) * r1 * f4(ln1w[c]) + f4(ln1b[c])) * vv;
        float4 v2 = ((l2 - m2) * r2 * f4(ln2w[c]) + f4(ln2b[c])) * vv;
        float4 v3 = ((l3 - m3) * r3 * f4(ln3w[c]) + f4(ln3b[c])) * vv;
        const float* w1 = wt_p + c * 64 + o0;            // uniform -> s_load
        const float* w2 = wt_p + (76 + c) * 64 + o0;
        const float* w3 = wt_p + (152 + c) * 64 + o0;
#pragma unroll
        for (int i = 0; i < 8; i++)
            acc[i] += v1 * f4(w1[i]) + v2 * f4(w2[i]) + v3 * f4(w3[i]);
    }
#pragma unroll
    for (int i = 0; i < 8; i++)
        *(float4*)(outb + (size_t)(o0 + i) * HWSZ + px) = acc[i];
}

extern "C" void kernel_launch(void* const* d_in, const int* in_sizes, int n_in,
                              void* d_out, int out_size, void* d_ws, size_t ws_size,
                              hipStream_t stream) {
    const float* x    = (const float*)d_in[0];
    const float* wh   = (const float*)d_in[1];
    const float* wdw  = (const float*)d_in[2];
    const float* wp   = (const float*)d_in[3];
    const float* fftp = (const float*)d_in[4];
    const float* ln1w = (const float*)d_in[5];
    const float* ln1b = (const float*)d_in[6];
    const float* ln2w = (const float*)d_in[7];
    const float* ln2b = (const float*)d_in[8];
    const float* ln3w = (const float*)d_in[9];
    const float* ln3b = (const float*)d_in[10];
    float* out = (float*)d_out;
    float* ws  = (float*)d_ws;

    const size_t wbytes = (size_t)(WT_H_ELEMS + WT_P_ELEMS) * 4;
    const size_t need = 2 * CH_ELEMS * 4 + wbytes;   // ~159.8 MB
    if (ws_size < need) return;

    float* hidden = ws;                         // [304][65536] per-batch conv output
    float* hdwb   = ws + CH_ELEMS;              // [304][65536] dw+fft output
    float* wt_h   = ws + 2 * CH_ELEMS;          // [64][304]
    float* wt_p   = wt_h + WT_H_ELEMS;          // [228][64]

    hipLaunchKernelGGL(k_prep, dim3(134), dim3(256), 0, stream, wh, wp, wt_h, wt_p);

    for (int b = 0; b < 2; b++) {
        const float* xb = x + (size_t)b * 64 * HWSZ;
        hipLaunchKernelGGL(k_conv1, dim3(256, 8), dim3(256), 0, stream, xb, wt_h, hidden);
        hipLaunchKernelGGL(k_dwfft, dim3(32, 76), dim3(256), 0, stream, hidden, wdw, hdwb, fftp);
        hipLaunchKernelGGL(k_outb, dim3(256), dim3(512), 0, stream, hdwb, wt_p,
                           ln1w, ln1b, ln2w, ln2b, ln3w, ln3b,
                           out + (size_t)b * 64 * HWSZ);
    }
}

// Round 7
// 469.050 us; speedup vs baseline: 1.7218x; 1.1292x over previous
//
#include <hip/hip_runtime.h>
#include <cstdint>
#include <cstddef>

// Problem constants
constexpr int HWSZ = 65536;                       // 256*256 pixels per image
constexpr size_t CH_ELEMS = (size_t)304 * HWSZ;   // per-batch 304-channel buffer elems
constexpr int WT_H_ELEMS = 64 * 304;
constexpr int WT_P_ELEMS = 228 * 64;

// LDS tile pitch: 261 % 32 = 5 (odd) -> dw tap reads spread across banks.
constexpr int TP = 261;
constexpr int GS = 10 * TP;   // per-group tile size (2610)

#define C1F 0.70710678118654752f
#define S2F 1.41421356237309505f

// float4 helpers
__device__ __forceinline__ float4 f4(float v) { return make_float4(v, v, v, v); }
__device__ __forceinline__ float4 operator+(float4 a, float4 b) { return make_float4(a.x+b.x, a.y+b.y, a.z+b.z, a.w+b.w); }
__device__ __forceinline__ float4 operator-(float4 a, float4 b) { return make_float4(a.x-b.x, a.y-b.y, a.z-b.z, a.w-b.w); }
__device__ __forceinline__ float4 operator*(float4 a, float4 b) { return make_float4(a.x*b.x, a.y*b.y, a.z*b.z, a.w*b.w); }
__device__ __forceinline__ float4& operator+=(float4& a, float4 b) { a.x+=b.x; a.y+=b.y; a.z+=b.z; a.w+=b.w; return a; }

// ---------------- prep: transpose weights for scalar-load GEMMs ----------------
__global__ __launch_bounds__(256) void k_prep(const float* __restrict__ wh,
                                              const float* __restrict__ wp,
                                              float* __restrict__ wt_h,
                                              float* __restrict__ wt_p) {
    int i = blockIdx.x * 256 + threadIdx.x;
    if (i < 64 * 304) {            // wh is [o=304][k=64] -> wt_h[k][o]
        int o = i / 64, k = i % 64;
        wt_h[k * 304 + o] = wh[i];
    }
    int j = i - 64 * 304;
    if (j >= 0 && j < 64 * 228) {  // wp is [o=64][c=228] -> wt_p[cc][o]
        int o = j / 228, cc = j % 228;
        wt_p[cc * 64 + o] = wp[j];
    }
}

// ---------------- 1x1 conv (one batch), grid (256, 8) ----------------
// k-chunked: 16 independent loads in flight ahead of 608 FMAs; acc[38] covers
// the whole y-group in one pass. VGPR ~62 -> high occupancy + deep ILP.
__global__ __launch_bounds__(256) void k_conv1(const float* __restrict__ xb,   // [64][65536]
                                               const float* __restrict__ wt,   // [k=64][o=304]
                                               float* __restrict__ hidden) {   // [304][65536]
    int sp = blockIdx.x * 256 + threadIdx.x;   // 0..65535
    int gbase = blockIdx.y * 38;               // out-channel base
    float acc[38];
#pragma unroll
    for (int i = 0; i < 38; i++) acc[i] = 0.f;
#pragma unroll
    for (int kc = 0; kc < 64; kc += 16) {
        float xv[16];
#pragma unroll
        for (int k = 0; k < 16; k++) xv[k] = xb[(size_t)(kc + k) * HWSZ + sp];
#pragma unroll
        for (int k = 0; k < 16; k++) {
            const float* wrow = wt + (kc + k) * 304 + gbase;   // uniform -> s_load
#pragma unroll
            for (int i = 0; i < 38; i++) acc[i] = fmaf(xv[k], wrow[i], acc[i]);
        }
    }
#pragma unroll
    for (int i = 0; i < 38; i++) hidden[(size_t)(gbase + i) * HWSZ + sp] = acc[i];
}

// ---------------- small FFT helpers (rfft8/irfft8 verified R2-R6) ----------------
__device__ __forceinline__ void rfft8(const float a[8], float Xr[5], float Xi[5]) {
    float u0 = a[0] + a[4], u1 = a[0] - a[4];
    float u2 = a[2] + a[6], u3 = a[2] - a[6];
    float u4 = a[1] + a[5], p  = a[1] - a[5];
    float u6 = a[3] + a[7], q  = a[3] - a[7];
    Xr[0] = u0 + u2 + u4 + u6;        Xi[0] = 0.f;
    Xr[1] = u1 + C1F * (p - q);       Xi[1] = -u3 - C1F * (p + q);
    Xr[2] = u0 - u2;                  Xi[2] = -(u4 - u6);
    Xr[3] = u1 - C1F * (p - q);       Xi[3] = u3 - C1F * (p + q);
    Xr[4] = u0 + u2 - u4 - u6;        Xi[4] = 0.f;
}

__device__ __forceinline__ void irfft8(const float Xr[5], const float Xi[5], float y[8]) {
    float A = Xr[0], B = Xr[4];
    float cr = Xr[1], ci = Xi[1], dr = Xr[2], di = Xi[2], er = Xr[3], ei = Xi[3];
    float abp = A + B, abm = A - B;
    float ccm = S2F * (cr - ci), ccp = S2F * (cr + ci);
    float eep = S2F * (er + ei), eem = S2F * (er - ei);
    float dr2 = 2.f * dr, di2 = 2.f * di;
    float cep = 2.f * (cr + er);
    float ci2 = 2.f * ci, ei2 = 2.f * ei;
    y[0] = abp + cep + dr2;
    y[1] = abm + ccm - di2 - eep;
    y[2] = abp - dr2 - ci2 + ei2;
    y[3] = abm - ccp + di2 + eem;
    y[4] = abp - cep + dr2;
    y[5] = abm - ccm - di2 + eep;
    y[6] = abp - dr2 + ci2 - ei2;
    y[7] = abm + ccp + di2 - eem;
}

// Branch-free butterfly stage applied to all 15 (Q,K,V x 5 bins) values:
// z' = A (.) z + B (.) partner   (complex per-lane coefficients)
__device__ __forceinline__ void bf_stage(float zr[15], float zi[15], int mask,
                                         float Ar, float Ai, float Br, float Bi) {
#pragma unroll
    for (int j = 0; j < 15; j++) {
        float or_ = __shfl_xor(zr[j], mask);
        float oi_ = __shfl_xor(zi[j], mask);
        float nr = Ar * zr[j] - Ai * zi[j] + Br * or_ - Bi * oi_;
        float ni = Ar * zi[j] + Ai * zr[j] + Br * oi_ + Bi * or_;
        zr[j] = nr; zi[j] = ni;
    }
}

// DIF forward FFT-8 over lanes (output scrambled: lane r holds bin bitrev3(r)).
__device__ __forceinline__ void cfwd15(float zr[15], float zi[15], int r) {
    int m = r & 3;
    float wr = (m == 0) ? 1.f : (m == 1) ? C1F : (m == 2) ? 0.f : -C1F;
    float wi = (m == 0) ? 0.f : (m == 1) ? -C1F : (m == 2) ? -1.f : -C1F;
    bool up = r >= 4;
    bf_stage(zr, zi, 4, up ? -wr : 1.f, up ? -wi : 0.f, up ? wr : 1.f, up ? wi : 0.f);
    bool u2 = (r & 2) != 0;
    float w2r = (r & 1) ? 0.f : 1.f, w2i = (r & 1) ? -1.f : 0.f;
    bf_stage(zr, zi, 2, u2 ? -w2r : 1.f, u2 ? -w2i : 0.f, u2 ? w2r : 1.f, u2 ? w2i : 0.f);
    bf_stage(zr, zi, 1, (r & 1) ? -1.f : 1.f, 0.f, 1.f, 0.f);
}

// DIT inverse FFT-8 (scrambled input -> natural order).
__device__ __forceinline__ void cinv15(float zr[15], float zi[15], int r) {
    bf_stage(zr, zi, 1, (r & 1) ? -1.f : 1.f, 0.f, 1.f, 0.f);
    float a2r, a2i, b2r, b2i;
    if ((r & 2) == 0) { a2r = 1.f; a2i = 0.f; b2r = (r & 1) ? 0.f : 1.f; b2i = (r & 1) ? 1.f : 0.f; }
    else             { a2r = (r & 1) ? 0.f : -1.f; a2i = (r & 1) ? -1.f : 0.f; b2r = 1.f; b2i = 0.f; }
    bf_stage(zr, zi, 2, a2r, a2i, b2r, b2i);
    int m = r & 3;
    float wr = (m == 0) ? 1.f : (m == 1) ? C1F : (m == 2) ? 0.f : -C1F;
    float wi = (m == 0) ? 0.f : (m == 1) ? C1F : (m == 2) ? 1.f : C1F;
    bool up = r >= 4;
    bf_stage(zr, zi, 4, up ? -wr : 1.f, up ? -wi : 0.f, up ? 1.f : wr, up ? 0.f : wi);
}

// ---------------- fused depthwise 3x3 + FFT attention (one batch) ----------------
// grid (32, 76): x=strip ph, y=triplet channel c.
__global__ __launch_bounds__(256) void k_dwfft(const float* __restrict__ hidden, // [304][65536]
                                               const float* __restrict__ wdw,    // [304][9]
                                               float* __restrict__ hdwb,         // [304][65536]
                                               const float* __restrict__ fft_param) {
    int ph = blockIdx.x, c = blockIdx.y;
    int t = threadIdx.x;
    int p = t >> 3, r = t & 7;                          // patch in strip, row in patch
    int br = ((r & 1) << 2) | (r & 2) | (r >> 2);       // bitrev3(r)
    int r0 = ph * 8;

    __shared__ float tile[4 * GS];                      // 4 groups x 10 rows x pitch 261

    // ---- stage: 2560 float4 slots, coalesced ----
#pragma unroll
    for (int j = 0; j < 10; j++) {
        int idx = j * 256 + t;
        int g = idx / 640;
        int rem = idx - g * 640;
        int rr = rem >> 6, c4 = rem & 63;
        int gr = r0 - 1 + rr;
        float4 val = f4(0.f);
        if (gr >= 0 && gr < 256)
            val = *(const float4*)(hidden + (size_t)(g * 76 + c) * HWSZ + gr * 256 + c4 * 4);
        float* d = tile + g * GS + rr * TP + c4 * 4;
        d[0] = val.x; d[1] = val.y; d[2] = val.z; d[3] = val.w;
    }
    __syncthreads();

    // z-slots: 0..4 = Q/out1, 5..9 = K/out3, 10..14 = V/out2
    float zr[15], zi[15];

    // ---- q/k/v: dw 3x3 in FFT thread layout + row rfft8 ----
    for (int g = 0; g < 3; g++) {
        float w[9];
#pragma unroll
        for (int i = 0; i < 9; i++) w[i] = wdw[(76 * g + c) * 9 + i];   // uniform
        float acc[8];
#pragma unroll
        for (int j = 0; j < 8; j++) acc[j] = 0.f;
#pragma unroll
        for (int rr = 0; rr < 3; rr++) {
            float v[10];
            int base = g * GS + (r + rr) * TP + p * 8;
            v[0] = (p > 0) ? tile[base - 1] : 0.f;
#pragma unroll
            for (int j = 0; j < 8; j++) v[j + 1] = tile[base + j];
            v[9] = (p < 31) ? tile[base + 8] : 0.f;
#pragma unroll
            for (int j = 0; j < 8; j++)
                acc[j] += w[rr * 3 + 0] * v[j] + w[rr * 3 + 1] * v[j + 1] + w[rr * 3 + 2] * v[j + 2];
        }
        float Xr[5], Xi[5];
        rfft8(acc, Xr, Xi);
        int s0 = (g == 0) ? 0 : (g == 1) ? 5 : 10;
#pragma unroll
        for (int v = 0; v < 5; v++) { zr[s0 + v] = Xr[v]; zi[s0 + v] = Xi[v]; }
    }

    // ---- vv: dw 3x3 in column layout, direct store ----
    {
        float w[9];
#pragma unroll
        for (int i = 0; i < 9; i++) w[i] = wdw[(228 + c) * 9 + i];
        float cl[10], cm[10], cr_[10];
#pragma unroll
        for (int rr = 0; rr < 10; rr++) {
            int base = 3 * GS + rr * TP + t;
            cm[rr]  = tile[base];
            cl[rr]  = (t > 0)   ? tile[base - 1] : 0.f;
            cr_[rr] = (t < 255) ? tile[base + 1] : 0.f;
        }
        float* outp = hdwb + (size_t)(228 + c) * HWSZ + (size_t)r0 * 256 + t;
#pragma unroll
        for (int rr = 0; rr < 8; rr++) {
            float s = cl[rr] * w[0] + cm[rr] * w[1] + cr_[rr] * w[2]
                    + cl[rr + 1] * w[3] + cm[rr + 1] * w[4] + cr_[rr + 1] * w[5]
                    + cl[rr + 2] * w[6] + cm[rr + 2] * w[7] + cr_[rr + 2] * w[8];
            outp[(size_t)rr * 256] = s;
        }
    }

    // ---- column FFTs (branch-free), pointwise mix, inverse ----
    cfwd15(zr, zi, r);

    const float inv64 = 0.015625f;
#pragma unroll
    for (int v = 0; v < 5; v++) {
        float pf = fft_param[(c * 8 + br) * 5 + v];
        float vr = zr[10 + v] * pf, vi = zi[10 + v] * pf;
        float qr = zr[v], qi = zi[v], kr = zr[5 + v], ki = zi[5 + v];
        float cr = qr * kr + qi * ki;          // qf * conj(kf)
        float ci = qi * kr - qr * ki;
        float m2q = cr * cr + ci * ci, m2v = vr * vr + vi * vi;
        float rq = rsqrtf(fmaxf(m2q, 1e-38f));
        float rv = rsqrtf(fmaxf(m2v, 1e-38f));
        float s  = sqrtf(m2v) * rq * inv64;    // |vf|/|qck| / 64
        float tt = sqrtf(m2q) * rv * inv64;    // |qck|/|vf| / 64
        zr[v] = cr * s;           zi[v] = ci * s;          // out1
        zr[10 + v] = vr * tt;     zi[10 + v] = vi * tt;    // out2
        zr[5 + v] = cr * inv64;   zi[5 + v] = ci * inv64;  // out3
    }

    cinv15(zr, zi, r);

    size_t obase = (size_t)c * HWSZ + (size_t)(r0 + r) * 256 + p * 8;
    float Xr[5], Xi[5], y[8];
#pragma unroll
    for (int v = 0; v < 5; v++) { Xr[v] = zr[v]; Xi[v] = zi[v]; }
    irfft8(Xr, Xi, y);  // out1 -> q region
    { float4 f0 = {y[0],y[1],y[2],y[3]}, f1 = {y[4],y[5],y[6],y[7]};
      *(float4*)(hdwb + obase) = f0; *(float4*)(hdwb + obase + 4) = f1; }
#pragma unroll
    for (int v = 0; v < 5; v++) { Xr[v] = zr[10 + v]; Xi[v] = zi[10 + v]; }
    irfft8(Xr, Xi, y);  // out2 -> k region
    { float4 f0 = {y[0],y[1],y[2],y[3]}, f1 = {y[4],y[5],y[6],y[7]};
      *(float4*)(hdwb + obase + (size_t)76 * HWSZ) = f0;
      *(float4*)(hdwb + obase + (size_t)76 * HWSZ + 4) = f1; }
#pragma unroll
    for (int v = 0; v < 5; v++) { Xr[v] = zr[5 + v]; Xi[v] = zi[5 + v]; }
    irfft8(Xr, Xi, y);  // out3 -> v region
    { float4 f0 = {y[0],y[1],y[2],y[3]}, f1 = {y[4],y[5],y[6],y[7]};
      *(float4*)(hdwb + obase + (size_t)152 * HWSZ) = f0;
      *(float4*)(hdwb + obase + (size_t)152 * HWSZ + 4) = f1; }
}

// ---------------- layernorm + gate + final projection (one batch) ----------------
// R4-exact shape (512 thr, 4 px/lane float4, 256 blocks) + 2-deep c-pipeline.
__global__ __launch_bounds__(512) void k_outb(const float* __restrict__ hdwb,
                                              const float* __restrict__ wt_p, // [c=228][o=64]
                                              const float* __restrict__ ln1w, const float* __restrict__ ln1b,
                                              const float* __restrict__ ln2w, const float* __restrict__ ln2b,
                                              const float* __restrict__ ln3w, const float* __restrict__ ln3b,
                                              float* __restrict__ outb) {
    int lane = threadIdx.x & 63;
    int w = threadIdx.x >> 6;                 // wave id 0..7
    int px = blockIdx.x * 256 + lane * 4;     // 4 pixels per lane
    const float* hb = hdwb + px;

    float4 s1 = f4(0), q1 = f4(0), s2 = f4(0), q2 = f4(0), s3 = f4(0), q3 = f4(0);
    for (int c = w; c < 76; c += 8) {
        float4 v1 = *(const float4*)(hb + (size_t)c * HWSZ);
        float4 v2 = *(const float4*)(hb + (size_t)(76 + c) * HWSZ);
        float4 v3 = *(const float4*)(hb + (size_t)(152 + c) * HWSZ);
        s1 += v1; q1 += v1 * v1;
        s2 += v2; q2 += v2 * v2;
        s3 += v3; q3 += v3 * v3;
    }
    __shared__ float4 sred[6][8][64];
    sred[0][w][lane] = s1; sred[1][w][lane] = q1;
    sred[2][w][lane] = s2; sred[3][w][lane] = q2;
    sred[4][w][lane] = s3; sred[5][w][lane] = q3;
    __syncthreads();
    s1 = f4(0); q1 = f4(0); s2 = f4(0); q2 = f4(0); s3 = f4(0); q3 = f4(0);
#pragma unroll
    for (int k = 0; k < 8; k++) {
        s1 += sred[0][k][lane]; q1 += sred[1][k][lane];
        s2 += sred[2][k][lane]; q2 += sred[3][k][lane];
        s3 += sred[4][k][lane]; q3 += sred[5][k][lane];
    }

    const float4 invE = f4(1.f / 76.f);
    float4 m1 = s1 * invE, m2 = s2 * invE, m3 = s3 * invE;
    float4 vr1 = q1 * invE - m1 * m1, vr2 = q2 * invE - m2 * m2, vr3 = q3 * invE - m3 * m3;
    float4 r1, r2, r3;
    r1.x = rsqrtf(fmaxf(vr1.x, 0.f) + 1e-5f); r1.y = rsqrtf(fmaxf(vr1.y, 0.f) + 1e-5f);
    r1.z = rsqrtf(fmaxf(vr1.z, 0.f) + 1e-5f); r1.w = rsqrtf(fmaxf(vr1.w, 0.f) + 1e-5f);
    r2.x = rsqrtf(fmaxf(vr2.x, 0.f) + 1e-5f); r2.y = rsqrtf(fmaxf(vr2.y, 0.f) + 1e-5f);
    r2.z = rsqrtf(fmaxf(vr2.z, 0.f) + 1e-5f); r2.w = rsqrtf(fmaxf(vr2.w, 0.f) + 1e-5f);
    r3.x = rsqrtf(fmaxf(vr3.x, 0.f) + 1e-5f); r3.y = rsqrtf(fmaxf(vr3.y, 0.f) + 1e-5f);
    r3.z = rsqrtf(fmaxf(vr3.z, 0.f) + 1e-5f); r3.w = rsqrtf(fmaxf(vr3.w, 0.f) + 1e-5f);

    int o0 = w * 8;
    float4 acc[8];
#pragma unroll
    for (int i = 0; i < 8; i++) acc[i] = f4(0);

    // software pipeline: prefetch c+1 loads during c compute
    float4 pv = *(const float4*)(hb + (size_t)228 * HWSZ);
    float4 p1 = *(const float4*)(hb);
    float4 p2 = *(const float4*)(hb + (size_t)76 * HWSZ);
    float4 p3 = *(const float4*)(hb + (size_t)152 * HWSZ);
    for (int c = 0; c < 76; c++) {
        float4 vv = pv, l1 = p1, l2 = p2, l3 = p3;
        if (c < 75) {
            pv = *(const float4*)(hb + (size_t)(229 + c) * HWSZ);
            p1 = *(const float4*)(hb + (size_t)(1 + c) * HWSZ);
            p2 = *(const float4*)(hb + (size_t)(77 + c) * HWSZ);
            p3 = *(const float4*)(hb + (size_t)(153 + c) * HWSZ);
        }
        float4 v1 = ((l1 - m1) * r1 * f4(ln1w[c]) + f4(ln1b[c])) * vv;
        float4 v2 = ((l2 - m2) * r2 * f4(ln2w[c]) + f4(ln2b[c])) * vv;
        float4 v3 = ((l3 - m3) * r3 * f4(ln3w[c]) + f4(ln3b[c])) * vv;
        const float* w1 = wt_p + c * 64 + o0;            // uniform -> s_load
        const float* w2 = wt_p + (76 + c) * 64 + o0;
        const float* w3 = wt_p + (152 + c) * 64 + o0;
#pragma unroll
        for (int i = 0; i < 8; i++)
            acc[i] += v1 * f4(w1[i]) + v2 * f4(w2[i]) + v3 * f4(w3[i]);
    }
#pragma unroll
    for (int i = 0; i < 8; i++)
        *(float4*)(outb + (size_t)(o0 + i) * HWSZ + px) = acc[i];
}

extern "C" void kernel_launch(void* const* d_in, const int* in_sizes, int n_in,
                              void* d_out, int out_size, void* d_ws, size_t ws_size,
                              hipStream_t stream) {
    const float* x    = (const float*)d_in[0];
    const float* wh   = (const float*)d_in[1];
    const float* wdw  = (const float*)d_in[2];
    const float* wp   = (const float*)d_in[3];
    const float* fftp = (const float*)d_in[4];
    const float* ln1w = (const float*)d_in[5];
    const float* ln1b = (const float*)d_in[6];
    const float* ln2w = (const float*)d_in[7];
    const float* ln2b = (const float*)d_in[8];
    const float* ln3w = (const float*)d_in[9];
    const float* ln3b = (const float*)d_in[10];
    float* out = (float*)d_out;
    float* ws  = (float*)d_ws;

    const size_t wbytes = (size_t)(WT_H_ELEMS + WT_P_ELEMS) * 4;
    const size_t need = 2 * CH_ELEMS * 4 + wbytes;   // ~159.8 MB
    if (ws_size < need) return;

    float* hidden = ws;                         // [304][65536] per-batch conv output
    float* hdwb   = ws + CH_ELEMS;              // [304][65536] dw+fft output
    float* wt_h   = ws + 2 * CH_ELEMS;          // [64][304]
    float* wt_p   = wt_h + WT_H_ELEMS;          // [228][64]

    hipLaunchKernelGGL(k_prep, dim3(134), dim3(256), 0, stream, wh, wp, wt_h, wt_p);

    for (int b = 0; b < 2; b++) {
        const float* xb = x + (size_t)b * 64 * HWSZ;
        hipLaunchKernelGGL(k_conv1, dim3(256, 8), dim3(256), 0, stream, xb, wt_h, hidden);
        hipLaunchKernelGGL(k_dwfft, dim3(32, 76), dim3(256), 0, stream, hidden, wdw, hdwb, fftp);
        hipLaunchKernelGGL(k_outb, dim3(256), dim3(512), 0, stream, hdwb, wt_p,
                           ln1w, ln1b, ln2w, ln2b, ln3w, ln3b,
                           out + (size_t)b * 64 * HWSZ);
    }
}